// Round 5
// baseline (182.448 us; speedup 1.0000x reference)
//
#include <hip/hip_runtime.h>
#include <cstdint>
#include <cstddef>

typedef short bf16x8 __attribute__((ext_vector_type(8)));
typedef float f32x4 __attribute__((ext_vector_type(4)));

#define EPS 1e-3f

__device__ __forceinline__ short f32_to_bf16s(float f) {
    union { float f; uint32_t u; } v; v.f = f;
    return (short)((v.u + 0x7FFFu + ((v.u >> 16) & 1u)) >> 16);
}
__device__ __forceinline__ float bf16s_to_f32(short s) {
    union { uint32_t u; float f; } v; v.u = ((uint32_t)(unsigned short)s) << 16;
    return v.f;
}

// K0: wt[kp][ci] = bf16(W[ci][kp]) (192x64); at[w][k] = bf16(A[p][v][w]) (32x96, k=p*25+v, zero-padded)
__global__ __launch_bounds__(256) void prep_kernel(const float* __restrict__ A,
                                                   const float* __restrict__ W,
                                                   unsigned short* __restrict__ wt,
                                                   unsigned short* __restrict__ at) {
    int idx = blockIdx.x * 256 + threadIdx.x;
    if (idx < 12288) {
        int kp = idx >> 6, ci = idx & 63;
        wt[idx] = (unsigned short)f32_to_bf16s(W[ci * 192 + kp]);
    } else {
        int j = idx - 12288;
        if (j < 3072) {
            int w = j / 96, k = j - w * 96;
            float val = 0.f;
            if (w < 25 && k < 75) {
                int p = k / 25, v = k - p * 25;
                val = A[(p * 25 + v) * 25 + w];
            }
            at[j] = (unsigned short)f32_to_bf16s(val);
        }
    }
}

// Mega: coalesced x->LDS staging + in-LDS window + conv GEMM + graph GEMM + BN/ReLU/res/ReLU.
// Block = (l-chunk of 8, n), 512 threads. CH=8 => 200 cols, GEMM2 l == wave id.
// LDS: R0 (13312 sh) = XsH[64][208] (halo, dead after p1b) -> xwL[8][1656] -> Ys[128][104]
//      XsB (13312 sh) = [64][208] body rows (also residual source)
__global__ __launch_bounds__(512, 4) void mega_kernel(
    const float* __restrict__ x,
    const unsigned short* __restrict__ wt,
    const unsigned short* __restrict__ at,
    const float* __restrict__ gamma, const float* __restrict__ beta,
    const float* __restrict__ mean, const float* __restrict__ var,
    float* __restrict__ out) {
    const int ch = blockIdx.x, n = blockIdx.y;
    const int l0 = ch * 8;
    const int tid = threadIdx.x;
    const int wv = tid >> 6, lane = tid & 63, q = lane >> 4, lcol = lane & 15;

    __shared__ __align__(16) short R0[13312];
    __shared__ __align__(16) short XsB[13312];
    __shared__ float scs[64], shs[64];

    // Early prefetch: b2 fragments (at, L2) + BN constants
    bf16x8 b2[2][3];
    #pragma unroll
    for (int nt = 0; nt < 2; ++nt)
        #pragma unroll
        for (int s = 0; s < 3; ++s)
            b2[nt][s] = *(const bf16x8*)(at + (size_t)(nt * 16 + lcol) * 96 + 32 * s + 8 * q);
    if (tid < 64) {
        float sc = gamma[tid] * rsqrtf(var[tid] + EPS);
        scs[tid] = sc;
        shs[tid] = beta[tid] - mean[tid] * sc;
    }

    // Phase 1a: fully-coalesced float4 staging of x[(l0-8)*25 .. (l0+8)*25) for all 64 ci -> bf16 LDS
    {
        const float* xn = x + (size_t)n * 480000;
        const int e0 = l0 * 25 - 200;
        #pragma unroll
        for (int rep = 0; rep < 13; ++rep) {
            int i = tid + rep * 512;
            if (i < 6400) {
                int ci = i / 100, j = i - ci * 100;
                int eg = e0 + 4 * j;
                float4 val = make_float4(0.f, 0.f, 0.f, 0.f);
                if (eg >= 0 && eg <= 7496)
                    val = *(const float4*)(xn + (size_t)ci * 7500 + eg);
                short4 sv;
                sv.x = f32_to_bf16s(val.x); sv.y = f32_to_bf16s(val.y);
                sv.z = f32_to_bf16s(val.z); sv.w = f32_to_bf16s(val.w);
                if (j < 50) *(short4*)&R0[ci * 208 + 4 * j] = sv;
                else        *(short4*)&XsB[ci * 208 + 4 * (j - 50)] = sv;
            }
        }
    }
    __syncthreads();

    // Phase 1b-A: read halo vals (XsH, aliased with xwL target) into registers
    float hv[4][8];
    #pragma unroll
    for (int rep = 0; rep < 3; ++rep) {
        int col = tid + rep * 512;               // < 1536
        int ci = col / 25, v = col - ci * 25;
        const short* hp = &R0[ci * 208 + v];
        #pragma unroll
        for (int m = 0; m < 8; ++m) hv[rep][m] = bf16s_to_f32(hp[m * 25]);
    }
    if (tid < 64) {
        int col = 1536 + tid;
        int ci = col / 25, v = col - ci * 25;
        const short* hp = &R0[ci * 208 + v];
        #pragma unroll
        for (int m = 0; m < 8; ++m) hv[3][m] = bf16s_to_f32(hp[m * 25]);
    }
    __syncthreads();   // all XsH reads done; R0 becomes xwL

    // Phase 1b-B: running 9-window, write xwL[qs=ci>>3][col*8 + (ci&7)]
    #pragma unroll
    for (int rep = 0; rep < 4; ++rep) {
        int col = (rep < 3) ? (tid + rep * 512) : (1536 + tid);
        bool act = (rep < 3) || (tid < 64);
        if (act) {
            int ci = col / 25, v = col - ci * 25;
            const short* bp = &XsB[ci * 208 + v];
            float bv[8];
            #pragma unroll
            for (int m = 0; m < 8; ++m) bv[m] = bf16s_to_f32(bp[m * 25]);
            float run = hv[rep][0] + hv[rep][1] + hv[rep][2] + hv[rep][3]
                      + hv[rep][4] + hv[rep][5] + hv[rep][6] + hv[rep][7];
            short* wb = &R0[(ci >> 3) * 1656 + (ci & 7)];
            #pragma unroll
            for (int j = 0; j < 8; ++j) {
                run += bv[j];
                wb[(j * 25 + v) * 8] = f32_to_bf16s(run);
                if (j < 7) run -= hv[rep][j];
            }
        }
    }
    __syncthreads();   // xwL ready

    // b1 fragments: B[k=ci][col], col tiles t = 8i+wv (valid t<13, rest safe garbage)
    bf16x8 b1[2][2];
    #pragma unroll
    for (int i = 0; i < 2; ++i) {
        int t = 8 * i + wv;
        int colb = 16 * t + lcol;
        if (colb > 207) colb = 207;
        #pragma unroll
        for (int s = 0; s < 2; ++s)
            b1[i][s] = *(const bf16x8*)&R0[(4 * s + q) * 1656 + colb * 8];
    }
    // prefetch a1 for group 0
    bf16x8 a1[3][2];
    #pragma unroll
    for (int mt = 0; mt < 3; ++mt)
        #pragma unroll
        for (int s = 0; s < 2; ++s)
            a1[mt][s] = *(const bf16x8*)(wt + (size_t)(mt * 16 + lcol) * 64 + 32 * s + 8 * q);
    __syncthreads();   // all xwL reads done; R0 becomes Ys

    // zero Ys pad k in [75,96)
    #pragma unroll
    for (int i = tid; i < 2688; i += 512) {
        int r = i / 21, kk = 75 + (i - r * 21);
        R0[r * 104 + kk] = 0;
    }

    #pragma unroll 1
    for (int g = 0; g < 4; ++g) {
        // GEMM1: M=48 (group g), N=200(+pad), K=64 — registers only
        f32x4 acc[3][2];
        #pragma unroll
        for (int mt = 0; mt < 3; ++mt)
            #pragma unroll
            for (int i = 0; i < 2; ++i) acc[mt][i] = (f32x4){0.f, 0.f, 0.f, 0.f};
        #pragma unroll
        for (int s = 0; s < 2; ++s)
            #pragma unroll
            for (int mt = 0; mt < 3; ++mt) {
                bf16x8 av = a1[mt][s];
                #pragma unroll
                for (int i = 0; i < 2; ++i)
                    acc[mt][i] = __builtin_amdgcn_mfma_f32_16x16x32_bf16(av, b1[i][s], acc[mt][i], 0, 0, 0);
            }
        // prefetch next group's a1 (hidden under staging barrier + GEMM2)
        {
            int gn = (g < 3) ? g + 1 : 3;
            #pragma unroll
            for (int mt = 0; mt < 3; ++mt)
                #pragma unroll
                for (int s = 0; s < 2; ++s)
                    a1[mt][s] = *(const bf16x8*)(wt + (size_t)(gn * 48 + mt * 16 + lcol) * 64 + 32 * s + 8 * q);
        }
        __syncthreads();   // previous GEMM2 Ys reads done
        // Stage D -> Ys[(ll*16+cl)*104 + 25p + v]
        #pragma unroll
        for (int mt = 0; mt < 3; ++mt)
            #pragma unroll
            for (int i = 0; i < 2; ++i) {
                int t = 8 * i + wv;
                int col = 16 * t + lcol;
                if (col < 200) {
                    int ll = col / 25, v = col - ll * 25;
                    #pragma unroll
                    for (int r = 0; r < 4; ++r) {
                        int kp = mt * 16 + 4 * q + r;
                        int cl = kp / 3, p = kp - cl * 3;
                        R0[(ll * 16 + cl) * 104 + 25 * p + v] = f32_to_bf16s(acc[mt][i][r]);
                    }
                }
            }
        __syncthreads();

        // GEMM2: wave wv owns l = wv; N=32 (2 nt tiles), K=96; fused epilogue
        const int l = wv;
        float res[2][4];
        #pragma unroll
        for (int nt = 0; nt < 2; ++nt) {
            int w = nt * 16 + lcol;
            int wr = (w < 25) ? w : 24;
            #pragma unroll
            for (int r = 0; r < 4; ++r)
                res[nt][r] = bf16s_to_f32(XsB[(g * 16 + 4 * q + r) * 208 + l * 25 + wr]);
        }
        bf16x8 a2[3];
        #pragma unroll
        for (int s = 0; s < 3; ++s)
            a2[s] = *(const bf16x8*)&R0[(l * 16 + lcol) * 104 + 32 * s + 8 * q];
        f32x4 c0 = {0.f, 0.f, 0.f, 0.f}, c1 = {0.f, 0.f, 0.f, 0.f};
        #pragma unroll
        for (int s = 0; s < 3; ++s) {
            c0 = __builtin_amdgcn_mfma_f32_16x16x32_bf16(a2[s], b2[0][s], c0, 0, 0, 0);
            c1 = __builtin_amdgcn_mfma_f32_16x16x32_bf16(a2[s], b2[1][s], c1, 0, 0, 0);
        }
        int lg = l0 + l;
        if (lg < 300) {
            #pragma unroll
            for (int nt = 0; nt < 2; ++nt) {
                int w = nt * 16 + lcol;
                if (w < 25) {
                    f32x4 cc = nt ? c1 : c0;
                    #pragma unroll
                    for (int r = 0; r < 4; ++r) {
                        int c = g * 16 + 4 * q + r;
                        float o = fmaxf(cc[r] * scs[c] + shs[c], 0.f);
                        out[((size_t)(n * 64 + c) * 300 + lg) * 25 + w] = fmaxf(o + res[nt][r], 0.f);
                    }
                }
            }
        }
    }
}

extern "C" void kernel_launch(void* const* d_in, const int* in_sizes, int n_in,
                              void* d_out, int out_size, void* d_ws, size_t ws_size,
                              hipStream_t stream) {
    const float* x     = (const float*)d_in[0];
    const float* A     = (const float*)d_in[1];
    const float* W     = (const float*)d_in[2];
    const float* gamma = (const float*)d_in[3];
    const float* beta  = (const float*)d_in[4];
    const float* mean  = (const float*)d_in[5];
    const float* var   = (const float*)d_in[6];
    float* out = (float*)d_out;

    char* ws = (char*)d_ws;
    unsigned short* wt = (unsigned short*)ws;               // 24,576 B
    unsigned short* at = (unsigned short*)(ws + 24576);     // 6,144 B

    prep_kernel<<<60, 256, 0, stream>>>(A, W, wt, at);
    mega_kernel<<<dim3(38, 32), 512, 0, stream>>>(x, wt, at, gamma, beta, mean, var, out);
}

// Round 6
// 165.093 us; speedup vs baseline: 1.1051x; 1.1051x over previous
//
#include <hip/hip_runtime.h>
#include <cstdint>
#include <cstddef>

typedef short bf16x8 __attribute__((ext_vector_type(8)));
typedef float f32x4 __attribute__((ext_vector_type(4)));

#define EPS 1e-3f

__device__ __forceinline__ short f32_to_bf16s(float f) {
    union { float f; uint32_t u; } v; v.f = f;
    return (short)((v.u + 0x7FFFu + ((v.u >> 16) & 1u)) >> 16);
}

// K0: wt[kp][ci] = bf16(W[ci][kp]) (192x64); at[w][k] = bf16(A[p][v][w]) (32x96, k=p*25+v, zero-padded)
__global__ __launch_bounds__(256) void prep_kernel(const float* __restrict__ A,
                                                   const float* __restrict__ W,
                                                   unsigned short* __restrict__ wt,
                                                   unsigned short* __restrict__ at) {
    int idx = blockIdx.x * 256 + threadIdx.x;
    if (idx < 12288) {
        int kp = idx >> 6, ci = idx & 63;
        wt[idx] = (unsigned short)f32_to_bf16s(W[ci * 192 + kp]);
    } else {
        int j = idx - 12288;
        if (j < 3072) {
            int w = j / 96, k = j - w * 96;
            float val = 0.f;
            if (w < 25 && k < 75) {
                int p = k / 25, v = k - p * 25;
                val = A[(p * 25 + v) * 25 + w];
            }
            at[j] = (unsigned short)f32_to_bf16s(val);
        }
    }
}

// Mega, barrier-minimal: one __syncthreads total.
// Block = (l-chunk of 8, n), 512 threads; wave wv owns l = l0+wv end-to-end.
// xwL[qs=ci>>3][col][ci&7], col = l_local*25+v, per-qs stride 1656 shorts (207 cols).
// Ys: per-wave-private 16-row slab [wv*16+cl][104] — no cross-wave sharing => no g-loop barriers.
__global__ __launch_bounds__(512, 4) void mega_kernel(
    const float* __restrict__ x,
    const unsigned short* __restrict__ wt,
    const unsigned short* __restrict__ at,
    const float* __restrict__ gamma, const float* __restrict__ beta,
    const float* __restrict__ mean, const float* __restrict__ var,
    float* __restrict__ out) {
    const int ch = blockIdx.x, n = blockIdx.y;
    const int l0 = ch * 8;
    const int tid = threadIdx.x;
    const int wv = tid >> 6, lane = tid & 63, q = lane >> 4, lcol = lane & 15;

    __shared__ __align__(16) short xwL[13248];   // 8 * 1656
    __shared__ __align__(16) short Ys[13312];    // 128 rows * 104
    __shared__ float scs[64], shs[64];

    // b2 fragments (at, L2-resident) + BN constants — prefetched before phase 1
    bf16x8 b2[2][3];
    #pragma unroll
    for (int nt = 0; nt < 2; ++nt)
        #pragma unroll
        for (int s = 0; s < 3; ++s)
            b2[nt][s] = *(const bf16x8*)(at + (size_t)(nt * 16 + lcol) * 96 + 32 * s + 8 * q);
    if (tid < 64) {
        float sc = gamma[tid] * rsqrtf(var[tid] + EPS);
        scs[tid] = sc;
        shs[tid] = beta[tid] - mean[tid] * sc;
    }

    // Zero own Ys slab pad cols [72,104): wave-private, no barrier needed.
    #pragma unroll
    for (int i = lane; i < 512; i += 64) {
        int r = i >> 5, cc = 72 + (i & 31);
        Ys[(wv * 16 + r) * 104 + cc] = 0;
    }

    // Phase 1: per-(ci,v) running 9-window over l = l0..l0+7 -> xwL (bf16)
    #pragma unroll 1
    for (int rep = 0; rep < 4; ++rep) {
        int cidx = tid + rep * 512;
        if (cidx < 1600) {
            int ci = cidx / 25, v = cidx - ci * 25;
            const float* xp = x + (size_t)(n * 64 + ci) * 7500 + v;
            float vals[16];
            #pragma unroll
            for (int i = 0; i < 16; ++i) {
                int l = l0 - 8 + i;
                vals[i] = (l >= 0 && l < 300) ? xp[l * 25] : 0.f;
            }
            float run = vals[0] + vals[1] + vals[2] + vals[3]
                      + vals[4] + vals[5] + vals[6] + vals[7];
            short* wb = &xwL[(ci >> 3) * 1656 + (ci & 7)];
            #pragma unroll
            for (int j = 0; j < 8; ++j) {
                run += vals[j + 8];
                wb[(j * 25 + v) * 8] = f32_to_bf16s(run);
                run -= vals[j];
            }
        }
    }
    __syncthreads();   // the only barrier

    // b1 fragments: B[k=ci][col], cols wv*25 + nt*16 + lcol (<=206; cols>=200 are stale-but-finite,
    // their MFMA D-columns map to w>=25 and are never stored)
    bf16x8 b1[2][2];
    #pragma unroll
    for (int nt = 0; nt < 2; ++nt) {
        int col = wv * 25 + nt * 16 + lcol;
        #pragma unroll
        for (int s = 0; s < 2; ++s)
            b1[nt][s] = *(const bf16x8*)&xwL[(4 * s + q) * 1656 + col * 8];
    }

    const int lg = l0 + wv;
    const size_t outrow = ((size_t)n * 64 * 300 + lg) * 25;   // + c*7500 + w

    #pragma unroll 1
    for (int g = 0; g < 4; ++g) {
        // a1 fragments for this c-group (wt, L2-resident)
        bf16x8 a1[3][2];
        #pragma unroll
        for (int mt = 0; mt < 3; ++mt)
            #pragma unroll
            for (int s = 0; s < 2; ++s)
                a1[mt][s] = *(const bf16x8*)(wt + (size_t)(g * 48 + mt * 16 + lcol) * 64 + 32 * s + 8 * q);

        // GEMM1: M=48 (kp of group g), N=32 (own l, v+pad), K=64
        f32x4 acc[3][2];
        #pragma unroll
        for (int mt = 0; mt < 3; ++mt)
            #pragma unroll
            for (int nt = 0; nt < 2; ++nt) acc[mt][nt] = (f32x4){0.f, 0.f, 0.f, 0.f};
        #pragma unroll
        for (int s = 0; s < 2; ++s)
            #pragma unroll
            for (int mt = 0; mt < 3; ++mt) {
                bf16x8 av = a1[mt][s];
                #pragma unroll
                for (int nt = 0; nt < 2; ++nt)
                    acc[mt][nt] = __builtin_amdgcn_mfma_f32_16x16x32_bf16(av, b1[nt][s], acc[mt][nt], 0, 0, 0);
            }

        // Residual prefetch (L2-hot: same rows fetched by phase 1 of this block)
        float res[2][4];
        #pragma unroll
        for (int nt = 0; nt < 2; ++nt) {
            int w = nt * 16 + lcol;
            bool val = (w < 25) && (lg < 300);
            #pragma unroll
            for (int r = 0; r < 4; ++r) {
                int c = g * 16 + 4 * q + r;
                res[nt][r] = val ? x[outrow + (size_t)c * 7500 + w] : 0.f;
            }
        }

        // Stage D -> own Ys slab rows (wv*16+cl), col 25p+v   (wave-private, no barrier)
        #pragma unroll
        for (int mt = 0; mt < 3; ++mt)
            #pragma unroll
            for (int nt = 0; nt < 2; ++nt) {
                int v = nt * 16 + lcol;
                if (v < 25) {
                    #pragma unroll
                    for (int r = 0; r < 4; ++r) {
                        int kpl = mt * 16 + 4 * q + r;
                        int cl = kpl / 3, p = kpl - 3 * cl;
                        Ys[(wv * 16 + cl) * 104 + 25 * p + v] = f32_to_bf16s(acc[mt][nt][r]);
                    }
                }
            }

        // GEMM2: M=16 (cl), N=32 (w), K=96 — reads own slab (compiler orders via lgkmcnt)
        f32x4 c0 = {0.f, 0.f, 0.f, 0.f}, c1 = {0.f, 0.f, 0.f, 0.f};
        #pragma unroll
        for (int s = 0; s < 3; ++s) {
            bf16x8 a2 = *(const bf16x8*)&Ys[(wv * 16 + lcol) * 104 + 32 * s + 8 * q];
            c0 = __builtin_amdgcn_mfma_f32_16x16x32_bf16(a2, b2[0][s], c0, 0, 0, 0);
            c1 = __builtin_amdgcn_mfma_f32_16x16x32_bf16(a2, b2[1][s], c1, 0, 0, 0);
        }

        // Epilogue: BN + ReLU + residual + ReLU
        if (lg < 300) {
            #pragma unroll
            for (int nt = 0; nt < 2; ++nt) {
                int w = nt * 16 + lcol;
                if (w < 25) {
                    f32x4 cc = nt ? c1 : c0;
                    #pragma unroll
                    for (int r = 0; r < 4; ++r) {
                        int c = g * 16 + 4 * q + r;
                        float o = fmaxf(cc[r] * scs[c] + shs[c], 0.f);
                        out[outrow + (size_t)c * 7500 + w] = fmaxf(o + res[nt][r], 0.f);
                    }
                }
            }
        }
    }
}

extern "C" void kernel_launch(void* const* d_in, const int* in_sizes, int n_in,
                              void* d_out, int out_size, void* d_ws, size_t ws_size,
                              hipStream_t stream) {
    const float* x     = (const float*)d_in[0];
    const float* A     = (const float*)d_in[1];
    const float* W     = (const float*)d_in[2];
    const float* gamma = (const float*)d_in[3];
    const float* beta  = (const float*)d_in[4];
    const float* mean  = (const float*)d_in[5];
    const float* var   = (const float*)d_in[6];
    float* out = (float*)d_out;

    char* ws = (char*)d_ws;
    unsigned short* wt = (unsigned short*)ws;               // 24,576 B
    unsigned short* at = (unsigned short*)(ws + 24576);     // 6,144 B

    prep_kernel<<<60, 256, 0, stream>>>(A, W, wt, at);
    mega_kernel<<<dim3(38, 32), 512, 0, stream>>>(x, wt, at, gamma, beta, mean, var, out);
}